// Round 14
// baseline (44.574 us; speedup 1.0000x reference)
//
#include <hip/hip_runtime.h>

typedef __bf16 bf16x8 __attribute__((ext_vector_type(8)));
typedef float  f32x16 __attribute__((ext_vector_type(16)));

#define NI 256
#define NT 256
#define NL 32
#define NE 128
#define HW 49
#define NEG_INF (-3.0e38f)

// ws layout (bf16), validated R5/R8+ (32x32 fragment-linear):
//  wsA: frag gw = (i*2+mt)*8+ks, elem (gw*64+lane)*8+j
//       = img[i, e=ks*16+(lane>>5)*8+j, hw=min(mt*32+(lane&31),48)]   (4 MB)
//  wsB: frag gw = t*8+ks, elem (gw*64+lane)*8+j
//       = txt[t, l=lane&31, e=ks*16+(lane>>5)*8+j]                    (2 MB)

// ---------- pre-kernel: fp32 -> bf16 MFMA-fragment layout ----------
__global__ __launch_bounds__(256, 4)
void prep_kernel(const float* __restrict__ img,
                 const float* __restrict__ txt,
                 __bf16* __restrict__ wsA,
                 __bf16* __restrict__ wsB)
{
    const int tid  = threadIdx.x;
    const int wave = tid >> 6, lane = tid & 63;
    const int ml   = lane & 31, h = lane >> 5;
    const int bid  = blockIdx.x;
    if (bid < 1024) {                       // A-part: 4096 waves
        int gw = bid * 4 + wave;            // (i, mt, ks)
        int i  = gw >> 4, mt = (gw >> 3) & 1, ks = gw & 7;
        int m  = mt * 32 + ml; if (m > HW - 1) m = HW - 1;
        int e0 = ks * 16 + h * 8;
        const float* p = img + ((size_t)i * NE + e0) * HW + m;
        union { __bf16 b[8]; int4 v; } u;
        #pragma unroll
        for (int j = 0; j < 8; ++j) u.b[j] = (__bf16)p[j * HW];
        *(int4*)(wsA + ((size_t)gw * 64 + lane) * 8) = u.v;
    } else {                                // B-part: 2048 waves
        int gw = (bid - 1024) * 4 + wave;   // (t, ks)
        int t  = gw >> 3, ks = gw & 7;
        int e0 = ks * 16 + h * 8;
        const float* p = txt + ((size_t)t * NL + ml) * NE + e0;
        float4 f0 = *(const float4*)p;
        float4 f1 = *(const float4*)(p + 4);
        union { __bf16 b[8]; int4 v; } u;
        u.b[0] = (__bf16)f0.x; u.b[1] = (__bf16)f0.y;
        u.b[2] = (__bf16)f0.z; u.b[3] = (__bf16)f0.w;
        u.b[4] = (__bf16)f1.x; u.b[5] = (__bf16)f1.y;
        u.b[6] = (__bf16)f1.z; u.b[7] = (__bf16)f1.w;
        *(int4*)(wsB + ((size_t)gw * 64 + lane) * 8) = u.v;
    }
}

#define GLDS(gp, lp) __builtin_amdgcn_global_load_lds(                     \
        (const __attribute__((address_space(1))) void*)(gp),               \
        (__attribute__((address_space(3))) void*)(lp), 16, 0, 0)

// ---------- main kernel: OCCUPANCY-FIRST (4 waves/SIMD) ----------
// Block: 4 waves = 4 full images x 16-text chunk; grid 1024 = 64 ig x 16 tb
// = 4 blocks/CU (16 waves/CU), zero tail. VGPR <= 128, LDS 40 KB.
// Rounds of 2 texts: stage via global_load_lds (shared by 4 waves),
// 1 __syncthreads/round; 4 independent blocks/CU de-phase and fill the
// matrix pipe across each other's barriers/bubbles.
__global__ __launch_bounds__(256, 4)
void clip_match_kernel(const __bf16* __restrict__ wsA,
                       const __bf16* __restrict__ wsB,
                       const int* __restrict__ tlen,
                       const float* __restrict__ nlt,
                       float* __restrict__ out)
{
    const int tid  = threadIdx.x;
    const int wave = tid >> 6, lane = tid & 63;
    const int ml   = lane & 31, h = lane >> 5;
    const int tb   = blockIdx.x & 15;    // text chunk (16 texts)
    const int ig   = blockIdx.x >> 4;    // image group (4 images)
    const int im   = ig * 4 + wave;      // this wave's image

    __shared__ __align__(16) __bf16 buf[2][2 * 4096];   // 2 x 16 KB (2 texts)
    __shared__ __align__(16) float  colmax[4][16][32];  // 8 KB, wave-private

    // ---- A fragments: full image, fragment-linear, 16 dwordx4 (64 VGPR) ----
    bf16x8 afr0[8], afr1[8];
    {
        const __bf16* pa = wsA + (size_t)im * 8192 + (size_t)lane * 8;
        #pragma unroll
        for (int ks = 0; ks < 8; ++ks) {
            afr0[ks] = *(const bf16x8*)(pa + ks * 512);
            afr1[ks] = *(const bf16x8*)(pa + 4096 + ks * 512);
        }
    }

    const __bf16* csrc = wsB + (size_t)tb * 16 * 4096;

    // ---- prologue: stage texts 0,1 (16 KB = 16 segs; 4 segs/wave) ----
    #pragma unroll
    for (int q = 0; q < 4; ++q) {
        int s = wave * 4 + q;
        GLDS(csrc + s * 512 + lane * 8, &buf[0][s * 512] + lane * 8);
    }
    __syncthreads();

    int c = 0;
    #pragma unroll 1
    for (int rnd = 0; rnd < 8; ++rnd) {
        // stage next round into buf[c^1] (consumed after this round's barrier)
        if (rnd < 7) {
            const __bf16* nsrc = csrc + (size_t)(rnd + 1) * 8192;
            #pragma unroll
            for (int q = 0; q < 4; ++q) {
                int s = wave * 4 + q;
                GLDS(nsrc + s * 512 + lane * 8,
                     &buf[c ^ 1][s * 512] + lane * 8);
            }
        }

        const __bf16* __restrict__ bsrc = buf[c];
        #pragma unroll
        for (int ts = 0; ts < 2; ++ts) {
            const int t = rnd * 2 + ts;
            f32x16 acc0 = (f32x16)(0.f), acc1 = (f32x16)(0.f);
            // K in two half-batches: only 4 bfrag regs live at a time
            #pragma unroll
            for (int ks = 0; ks < 4; ++ks) {
                bf16x8 bf = *(const bf16x8*)(bsrc + ts * 4096
                                             + (ks * 64 + lane) * 8);
                acc0 = __builtin_amdgcn_mfma_f32_32x32x16_bf16(
                    afr0[ks], bf, acc0, 0, 0, 0);
                acc1 = __builtin_amdgcn_mfma_f32_32x32x16_bf16(
                    afr1[ks], bf, acc1, 0, 0, 0);
            }
            #pragma unroll
            for (int ks = 4; ks < 8; ++ks) {
                bf16x8 bf = *(const bf16x8*)(bsrc + ts * 4096
                                             + (ks * 64 + lane) * 8);
                acc0 = __builtin_amdgcn_mfma_f32_32x32x16_bf16(
                    afr0[ks], bf, acc0, 0, 0, 0);
                acc1 = __builtin_amdgcn_mfma_f32_32x32x16_bf16(
                    afr1[ks], bf, acc1, 0, 0, 0);
            }
            // partial max over rows; C/D: col=lane&31,
            // row r2=(reg&3)+8*(reg>>2)+4*h; acc0: m=r2 (all 16 valid);
            // acc1: m=32+r2 -> regs 0..7, plus reg8 (m=48) iff h==0
            float t0[8];
            #pragma unroll
            for (int k = 0; k < 8; ++k) t0[k] = fmaxf(acc0[2*k], acc0[2*k+1]);
            float t1[4];
            #pragma unroll
            for (int k = 0; k < 4; ++k) t1[k] = fmaxf(t0[2*k], t0[2*k+1]);
            float a0m = fmaxf(fmaxf(t1[0], t1[1]), fmaxf(t1[2], t1[3]));
            float u0[4];
            #pragma unroll
            for (int k = 0; k < 4; ++k) u0[k] = fmaxf(acc1[2*k], acc1[2*k+1]);
            float a1m = fmaxf(fmaxf(u0[0], u0[1]), fmaxf(u0[2], u0[3]));
            float ex  = (h == 0) ? acc1[8] : NEG_INF;
            float cm  = fmaxf(fmaxf(a0m, a1m), ex);
            cm = fmaxf(cm, __shfl_xor(cm, 32));     // merge h-halves
            if (h == 0) colmax[wave][t][ml] = cm;   // plain wave-private store
        }
        __syncthreads();
        c ^= 1;
    }

    // ---- epilogue (wave-private colmax; no extra barrier) ----
    {
        const float scale = expf(nlt[0]);
        const int t = lane & 15;             // text within chunk
        const int q = lane >> 4;             // col octet 0..3
        const float* row = &colmax[wave][t][q * 8];
        float4 a0 = *(const float4*)(row + 0);
        float4 a1 = *(const float4*)(row + 4);
        float s = ((a0.x + a0.y) + (a0.z + a0.w))
                + ((a1.x + a1.y) + (a1.z + a1.w));
        s += __shfl_xor(s, 16);
        s += __shfl_xor(s, 32);              // all 32 cols
        if (q == 0) {
            int tg = tb * 16 + t;
            float v = s * scale / (float)tlen[tg];
            out[im * NT + tg] = v;              // logits_per_image[i,t]
            out[NI * NT + tg * NI + im] = v;    // logits_per_text[t,i]
        }
    }
}

extern "C" void kernel_launch(void* const* d_in, const int* in_sizes, int n_in,
                              void* d_out, int out_size, void* d_ws, size_t ws_size,
                              hipStream_t stream)
{
    const float* img  = (const float*)d_in[0];
    const float* txt  = (const float*)d_in[1];
    const int*   tlen = (const int*)d_in[2];
    const float* nlt  = (const float*)d_in[3];
    float* out = (float*)d_out;

    __bf16* wsA = (__bf16*)d_ws;                 // 4 MB
    __bf16* wsB = wsA + (size_t)4096 * 512;      // 2 MB

    prep_kernel<<<dim3(1536), dim3(256), 0, stream>>>(img, txt, wsA, wsB);
    clip_match_kernel<<<dim3(1024), dim3(256), 0, stream>>>(wsA, wsB, tlen, nlt, out);
}

// Round 15
// 32.482 us; speedup vs baseline: 1.3723x; 1.3723x over previous
//
#include <hip/hip_runtime.h>

typedef int   v8i    __attribute__((ext_vector_type(8)));
typedef float f32x16 __attribute__((ext_vector_type(16)));

#define NI 256
#define NT 256
#define NL 32
#define NE 128
#define HW 49
#define NEG_INF (-3.0e38f)
#define SCALE1 0x7F7F7F7F   // e8m0 = 127 -> x1.0, all blocks

// ws layout (fp8 e4m3, MFMA 32x32x64 fragment-linear):
//  wsA: frag gw = (i*2+mt)*2+ks, byte j of lane l
//       = img[i, e = ks*64+(l>>5)*32+j, hw = min(mt*32+(l&31),48)]    (2 MB)
//  wsB: frag gw = t*2+ks, byte j of lane l
//       = txt[t, l_word = l&31, e = ks*64+(l>>5)*32+j]                (1 MB)
// A and B use the SAME k<->(lane,byte) map -> k-permutation cancels.

__device__ __forceinline__ unsigned char f32_to_e4m3(float f)
{
    unsigned fb = __float_as_uint(f);
    unsigned s  = (fb >> 24) & 0x80;
    int      e  = (int)((fb >> 23) & 0xFF);
    unsigned m  = fb & 0x7FFFFF;
    int ne = e - 120;                    // e - 127 + 7
    if (ne <= 0)  return (unsigned char)s;          // flush tiny -> +-0
    if (ne > 15) { ne = 15; m = 0x600000; }         // huge -> max (won't occur)
    unsigned base = ((unsigned)ne << 3) | (m >> 20);
    unsigned rem  = m & 0xFFFFF;
    if (rem > 0x80000 || (rem == 0x80000 && (base & 1))) base++;   // RNE
    if (base > 0x7E) base = 0x7E;                   // saturate to 448
    return (unsigned char)(s | base);
}

// ---------- pre-kernel: fp32 -> fp8 MFMA-fragment layout ----------
__global__ __launch_bounds__(256, 4)
void prep_kernel(const float* __restrict__ img,
                 const float* __restrict__ txt,
                 unsigned char* __restrict__ wsA,
                 unsigned char* __restrict__ wsB)
{
    const int tid  = threadIdx.x;
    const int wave = tid >> 6, lane = tid & 63;
    const int ml   = lane & 31, h = lane >> 5;
    const int bid  = blockIdx.x;
    union { unsigned char b[32]; int4 v[2]; } u;
    if (bid < 256) {                        // A-part: 1024 waves
        int gw = bid * 4 + wave;            // (i, mt, ks)
        int i  = gw >> 2, mt = (gw >> 1) & 1, ks = gw & 1;
        int m  = mt * 32 + ml; if (m > HW - 1) m = HW - 1;
        int e0 = ks * 64 + h * 32;
        const float* p = img + ((size_t)i * NE + e0) * HW + m;
        #pragma unroll
        for (int j = 0; j < 32; ++j) u.b[j] = f32_to_e4m3(p[j * HW]);
        int4* dst = (int4*)(wsA + (size_t)gw * 2048 + lane * 32);
        dst[0] = u.v[0]; dst[1] = u.v[1];
    } else {                                // B-part: 512 waves
        int gw = (bid - 256) * 4 + wave;    // (t, ks)
        int t  = gw >> 1, ks = gw & 1;
        int e0 = ks * 64 + h * 32;
        const float* p = txt + ((size_t)t * NL + ml) * NE + e0;
        #pragma unroll
        for (int q = 0; q < 8; ++q) {
            float4 f = *(const float4*)(p + q * 4);
            u.b[q*4+0] = f32_to_e4m3(f.x); u.b[q*4+1] = f32_to_e4m3(f.y);
            u.b[q*4+2] = f32_to_e4m3(f.z); u.b[q*4+3] = f32_to_e4m3(f.w);
        }
        int4* dst = (int4*)(wsB + (size_t)gw * 2048 + lane * 32);
        dst[0] = u.v[0]; dst[1] = u.v[1];
    }
}

// ---------- main kernel: MX-fp8 K=64, 4 MFMA per wave-text ----------
// Block: 4 waves = 4 images x 16-text chunk; grid 1024 = 64 ig x 16 tb
// = 4 blocks/CU (16 waves/CU), zero tail, ZERO barriers. Per text:
// 4 global dwordx4 (2 v8i frags) -> 4 mfma_scale (2 chains of 2) -> fmax
// tree -> 1 wave-private ds_write. Marginal-cost probe: MFMA work /4,
// B-bytes /2, reduce UNCHANGED vs R8-R14.
__global__ __launch_bounds__(256, 4)
void clip_match_kernel(const unsigned char* __restrict__ wsA,
                       const unsigned char* __restrict__ wsB,
                       const int* __restrict__ tlen,
                       const float* __restrict__ nlt,
                       float* __restrict__ out)
{
    const int tid  = threadIdx.x;
    const int wave = tid >> 6, lane = tid & 63;
    const int ml   = lane & 31, h = lane >> 5;
    const int tb   = blockIdx.x & 15;    // text chunk (16 texts)
    const int ig   = blockIdx.x >> 4;    // image group (4 images)
    const int im   = ig * 4 + wave;      // this wave's image

    // per-(text): 64 partial maxima (h*32+col); stride 68 breaks epi banks
    __shared__ __align__(16) float colmax[4][16][68];   // ~17 KB, wave-private

    // ---- A fragments: 4 x v8i = 32 VGPR ----
    const unsigned char* pa = wsA + (size_t)im * 8192 + lane * 32;
    v8i aA0 = *(const v8i*)(pa);            // mt0 ks0
    v8i aA1 = *(const v8i*)(pa + 2048);     // mt0 ks1
    v8i aB0 = *(const v8i*)(pa + 4096);     // mt1 ks0
    v8i aB1 = *(const v8i*)(pa + 6144);     // mt1 ks1

    const unsigned char* csrc = wsB + (size_t)tb * 16 * 4096 + lane * 32;
#define BFR(t, k) (*(const v8i*)(csrc + (size_t)(t) * 4096 + (k) * 2048))

#define COMPUTE(bk0, bk1, t)                                                \
    {                                                                       \
        f32x16 acc0 = __builtin_amdgcn_mfma_scale_f32_32x32x64_f8f6f4(      \
            aA0, bk0, (f32x16)(0.f), 0, 0, 0, SCALE1, 0, SCALE1);           \
        acc0 = __builtin_amdgcn_mfma_scale_f32_32x32x64_f8f6f4(             \
            aA1, bk1, acc0, 0, 0, 0, SCALE1, 0, SCALE1);                    \
        f32x16 acc1 = __builtin_amdgcn_mfma_scale_f32_32x32x64_f8f6f4(      \
            aB0, bk0, (f32x16)(0.f), 0, 0, 0, SCALE1, 0, SCALE1);           \
        acc1 = __builtin_amdgcn_mfma_scale_f32_32x32x64_f8f6f4(             \
            aB1, bk1, acc1, 0, 0, 0, SCALE1, 0, SCALE1);                    \
        /* partial max over this h-half's rows; C/D (shape-determined):    \
           col=lane&31, row r2=(reg&3)+8*(reg>>2)+4*h; acc0: m=r2 (all     \
           16 valid); acc1: m=32+r2 -> regs 0..7, +reg8 (m=48) iff h==0 */ \
        float t0[8];                                                        \
        _Pragma("unroll")                                                   \
        for (int k = 0; k < 8; ++k) t0[k] = fmaxf(acc0[2*k], acc0[2*k+1]);  \
        float t1[4];                                                        \
        _Pragma("unroll")                                                   \
        for (int k = 0; k < 4; ++k) t1[k] = fmaxf(t0[2*k], t0[2*k+1]);      \
        float a0m = fmaxf(fmaxf(t1[0], t1[1]), fmaxf(t1[2], t1[3]));        \
        float u0[4];                                                        \
        _Pragma("unroll")                                                   \
        for (int k = 0; k < 4; ++k) u0[k] = fmaxf(acc1[2*k], acc1[2*k+1]);  \
        float a1m = fmaxf(fmaxf(u0[0], u0[1]), fmaxf(u0[2], u0[3]));        \
        float ex  = (h == 0) ? acc1[8] : NEG_INF;                           \
        colmax[wave][t][lane] = fmaxf(fmaxf(a0m, a1m), ex);                 \
    }

    // software pipeline, 1 text deep; ~115 VGPR: no pressure to sink loads
    v8i c0 = BFR(0, 0), c1 = BFR(0, 1);
    #pragma unroll 1
    for (int it = 0; it < 8; ++it) {
        const int t = 2 * it;
        v8i n0 = BFR(t + 1, 0), n1 = BFR(t + 1, 1);
        COMPUTE(c0, c1, t)
        if (it < 7) { c0 = BFR(t + 2, 0); c1 = BFR(t + 2, 1); }
        COMPUTE(n0, n1, t + 1)
    }
#undef COMPUTE
#undef BFR

    // ---- epilogue: merge h-halves, sum 32 cols, write both mirrors ----
    {
        const float scale = expf(nlt[0]);
        const int t = lane & 15;             // text within chunk
        const int q = lane >> 4;             // col octet 0..3
        const float* r0 = &colmax[wave][t][q * 8];        // h-part 0
        const float* r1 = &colmax[wave][t][32 + q * 8];   // h-part 1
        float4 a0 = *(const float4*)(r0 + 0);
        float4 a1 = *(const float4*)(r0 + 4);
        float4 c0 = *(const float4*)(r1 + 0);
        float4 c1 = *(const float4*)(r1 + 4);
        float s = (fmaxf(a0.x, c0.x) + fmaxf(a0.y, c0.y))
                + (fmaxf(a0.z, c0.z) + fmaxf(a0.w, c0.w))
                + (fmaxf(a1.x, c1.x) + fmaxf(a1.y, c1.y))
                + (fmaxf(a1.z, c1.z) + fmaxf(a1.w, c1.w));
        s += __shfl_xor(s, 16);
        s += __shfl_xor(s, 32);              // sum over all 4 octets
        if (q == 0) {
            int tg = tb * 16 + t;
            float v = s * scale / (float)tlen[tg];
            out[im * NT + tg] = v;              // logits_per_image[i,t]
            out[NI * NT + tg * NI + im] = v;    // logits_per_text[t,i]
        }
    }
}

extern "C" void kernel_launch(void* const* d_in, const int* in_sizes, int n_in,
                              void* d_out, int out_size, void* d_ws, size_t ws_size,
                              hipStream_t stream)
{
    const float* img  = (const float*)d_in[0];
    const float* txt  = (const float*)d_in[1];
    const int*   tlen = (const int*)d_in[2];
    const float* nlt  = (const float*)d_in[3];
    float* out = (float*)d_out;

    unsigned char* wsA = (unsigned char*)d_ws;           // 2 MB
    unsigned char* wsB = wsA + (size_t)2 * 1024 * 1024;  // 1 MB

    prep_kernel<<<dim3(384), dim3(256), 0, stream>>>(img, txt, wsA, wsB);
    clip_match_kernel<<<dim3(1024), dim3(256), 0, stream>>>(wsA, wsB, tlen, nlt, out);
}